// Round 12
// baseline (126.702 us; speedup 1.0000x reference)
//
#include <hip/hip_runtime.h>
#include <math.h>

#pragma clang fp contract(off)

#define NRAYS 4096
#define NS 512
#define NEL (NRAYS * NS)          // 2097152
#define NEL4 (NEL / 4)            // 524288 uint4
#define TOPK 4000u
#define TOPK_NB 256
#define CAPN 5120                 // per-block LDS capture capacity

// d_out layout (floats), concatenated in reference return order
#define OFF_W     ((size_t)0)
#define OFF_BG    ((size_t)2097152)
#define OFF_DEPTH ((size_t)2101248)
#define OFF_FULL  ((size_t)2105344)
#define OFF_INV   ((size_t)4202496)

// ws state slots (uints)
#define ST_TIEN  6
#define ST_TK1   8
#define ST_TK2   9
#define ST_TK3   10
#define ST_TK4   11
#define ST_OVF   12
#define ST_LN    13
#define TIE_CAP  8192u

#define AGLD(p) __hip_atomic_load((p), __ATOMIC_RELAXED, __HIP_MEMORY_SCOPE_AGENT)
#define AGST(p, v) __hip_atomic_store((p), (v), __ATOMIC_RELAXED, __HIP_MEMORY_SCOPE_AGENT)
#define TICKET(p) __hip_atomic_fetch_add((p), 1u, __ATOMIC_RELAXED, __HIP_MEMORY_SCOPE_AGENT)

__device__ __forceinline__ float tri_sample(const float* __restrict__ vol, int R,
                                            float cx, float cy, float cz) {
  #pragma clang fp contract(off)
  float c0 = fminf(fmaxf(cx, -1.0f), 1.0f);
  float c1 = fminf(fmaxf(cy, -1.0f), 1.0f);
  float c2 = fminf(fmaxf(cz, -1.0f), 1.0f);
  float fR = (float)(R - 1);
  float x = (c0 + 1.0f) * 0.5f * fR;
  float y = (c1 + 1.0f) * 0.5f * fR;
  float z = (c2 + 1.0f) * 0.5f * fR;
  float xf = fminf(fmaxf(floorf(x), 0.0f), (float)(R - 2));
  float yf = fminf(fmaxf(floorf(y), 0.0f), (float)(R - 2));
  float zf = fminf(fmaxf(floorf(z), 0.0f), (float)(R - 2));
  int x0 = (int)xf, y0 = (int)yf, z0 = (int)zf;
  float xd = x - xf, yd = y - yf, zd = z - zf;
  const float* p = vol + ((size_t)z0 * R + (size_t)y0) * R + (size_t)x0;
  float c000 = p[0], c001 = p[1];
  float c010 = p[R], c011 = p[R + 1];
  const float* q = p + (size_t)R * R;
  float c100 = q[0], c101 = q[1];
  float c110 = q[R], c111 = q[R + 1];
  float omx = 1.0f - xd, omy = 1.0f - yd, omz = 1.0f - zd;
  float c00 = c000 * omx + c001 * xd;
  float c01 = c010 * omx + c011 * xd;
  float c10 = c100 * omx + c101 * xd;
  float c11 = c110 * omx + c111 * xd;
  float a0 = c00 * omy + c01 * yd;
  float a1 = c10 * omy + c11 * yd;
  return a0 * omz + a1 * zd;
}

// density_grid and prob_grid are both 256^3: identical offsets + lerp weights,
// so one address computation feeds both 8-corner fetches (16 loads in flight).
__device__ __forceinline__ void tri_pair256(const float* __restrict__ va,
                                            const float* __restrict__ vb,
                                            float cx, float cy, float cz,
                                            float& ra, float& rb) {
  #pragma clang fp contract(off)
  const int R = 256;
  float c0 = fminf(fmaxf(cx, -1.0f), 1.0f);
  float c1 = fminf(fmaxf(cy, -1.0f), 1.0f);
  float c2 = fminf(fmaxf(cz, -1.0f), 1.0f);
  float fR = (float)(R - 1);
  float x = (c0 + 1.0f) * 0.5f * fR;
  float y = (c1 + 1.0f) * 0.5f * fR;
  float z = (c2 + 1.0f) * 0.5f * fR;
  float xf = fminf(fmaxf(floorf(x), 0.0f), (float)(R - 2));
  float yf = fminf(fmaxf(floorf(y), 0.0f), (float)(R - 2));
  float zf = fminf(fmaxf(floorf(z), 0.0f), (float)(R - 2));
  int x0 = (int)xf, y0 = (int)yf, z0 = (int)zf;
  float xd = x - xf, yd = y - yf, zd = z - zf;
  size_t off = ((size_t)z0 * R + (size_t)y0) * R + (size_t)x0;
  const float* p = va + off;
  const float* q = p + (size_t)R * R;
  float a000 = p[0], a001 = p[1], a010 = p[R], a011 = p[R + 1];
  float a100 = q[0], a101 = q[1], a110 = q[R], a111 = q[R + 1];
  const float* pp = vb + off;
  const float* qq = pp + (size_t)R * R;
  float b000 = pp[0], b001 = pp[1], b010 = pp[R], b011 = pp[R + 1];
  float b100 = qq[0], b101 = qq[1], b110 = qq[R], b111 = qq[R + 1];
  float omx = 1.0f - xd, omy = 1.0f - yd, omz = 1.0f - zd;
  {
    float c00 = a000 * omx + a001 * xd;
    float c01 = a010 * omx + a011 * xd;
    float c10 = a100 * omx + a101 * xd;
    float c11 = a110 * omx + a111 * xd;
    float a0 = c00 * omy + c01 * yd;
    float a1 = c10 * omy + c11 * yd;
    ra = a0 * omz + a1 * zd;
  }
  {
    float c00 = b000 * omx + b001 * xd;
    float c01 = b010 * omx + b011 * xd;
    float c10 = b100 * omx + b101 * xd;
    float c11 = b110 * omx + b111 * xd;
    float a0 = c00 * omy + c01 * yd;
    float a1 = c10 * omy + c11 * yd;
    rb = a0 * omz + a1 * zd;
  }
}

// 4 exact left-to-right chain steps; stores inclusive products as one float4.
#define CH4(V, IDX)                                        \
  {                                                        \
    float t0_ = T * ((1.0f - (V).x) + 1e-10f);             \
    float t1_ = t0_ * ((1.0f - (V).y) + 1e-10f);           \
    float t2_ = t1_ * ((1.0f - (V).z) + 1e-10f);           \
    float t3_ = t2_ * ((1.0f - (V).w) + 1e-10f);           \
    Ti4[IDX] = make_float4(t0_, t1_, t2_, t3_);            \
    T = t3_;                                               \
  }

// Block (256 thr) per ray. Up to 2 chunks of 256 samples; alpha+density+prob
// corners all fetched in parallel in phase 1 (prob lerp'd immediately, 1 reg
// survives the barrier) -> phase 2 is pure arithmetic. t0-only pipelined
// cumprod, bit-exact numpy left-to-right rounding. Chunk-end early termination
// (T<=1e-4): processed chunks bit-exact; skipped samples have ref-w <= 1e-4 so
// mask bits exact, |depth err| <= ~7e-4 (threshold 4.4e-2). ZERO global
// atomics (round-8/9 lesson: hot-line atomics cost ~250us).
__global__ __launch_bounds__(256) void k_march(
    const float* __restrict__ ro, const float* __restrict__ rd,
    const float* __restrict__ dens, const float* __restrict__ prb,
    const float* __restrict__ alpv, float* __restrict__ out) {
  #pragma clang fp contract(off)
  const float STEP = (float)(3.0 * 1.7320508075688772 / 512.0);
  const float DIST = (float)((3.0 * 1.7320508075688772 / 512.0) * 25.0);
  const float INVG = 2.0f / 3.0f;
  int r = blockIdx.x;
  int t = threadIdx.x;
  __shared__ __align__(16) float s_alpha[272];   // 256 + 16 pad (prefetch overrun)
  __shared__ __align__(16) float s_Ti[256];      // inclusive products for chunk
  __shared__ float s_red[256];
  __shared__ float s_Tstart, s_bg;
  __shared__ unsigned s_term;

  float ox = ro[r * 3 + 0], oy = ro[r * 3 + 1], oz = ro[r * 3 + 2];
  float dx = rd[r * 3 + 0], dy = rd[r * 3 + 1], dz = rd[r * 3 + 2];
  float vx = (dx == 0.0f) ? 1e-6f : dx;
  float vy = (dy == 0.0f) ? 1e-6f : dy;
  float vz = (dz == 0.0f) ? 1e-6f : dz;
  float tmin;
  {
    float rax = (1.5f - ox) / vx, rbx = (-1.5f - ox) / vx;
    float ray = (1.5f - oy) / vy, rby = (-1.5f - oy) / vy;
    float raz = (1.5f - oz) / vz, rbz = (-1.5f - oz) / vz;
    float m0 = fminf(rax, rbx), m1 = fminf(ray, rby), m2 = fminf(raz, rbz);
    tmin = fmaxf(fmaxf(m0, m1), m2);
    tmin = fminf(fmaxf(tmin, 2.0f), 6.0f);
  }

  unsigned rb = (unsigned)r * NS;
  float Tcarry = 1.0f;     // meaningful on t0 only
  float dsum = 0.0f;
  int cproc = 2;

  for (int c = 0; c < 2; ++c) {
    int s = c * 256 + t;
    float ts = tmin + STEP * (float)s;
    float px = ox + dx * ts;
    float py = oy + dy * ts;
    float pz = oz + dz * ts;
    bool inb = !((-1.5f > px) || (px > 1.5f) || (-1.5f > py) || (py > 1.5f) ||
                 (-1.5f > pz) || (pz > 1.5f));
    float a = 0.0f, pv = 0.0f;
    if (inb) {
      float nx = (px + 1.5f) * INVG - 1.0f;
      float ny = (py + 1.5f) * INVG - 1.0f;
      float nz = (pz + 1.5f) * INVG - 1.0f;
      float al = tri_sample(alpv, 128, nx, ny, nz);
      float feat;
      tri_pair256(dens, prb, nx, ny, nz, feat, pv);   // 16 loads, shared addrs
      if (al > 0.001f) {
        float xx = feat + (-10.0f);
        float sp = fmaxf(xx, 0.0f) + log1pf(expf(-fabsf(xx)));
        a = 1.0f - expf(-(sp * DIST));
      }
    }
    s_alpha[t] = a;
    __syncthreads();

    // t0 pipelined serial cumprod: prefetch segment k+1 while chaining seg k.
    if (t == 0) {
      s_Tstart = Tcarry;
      float T = Tcarry;
      const float4* a4 = (const float4*)s_alpha;
      float4* Ti4 = (float4*)s_Ti;
      float4 A0 = a4[0], A1 = a4[1], A2 = a4[2], A3 = a4[3];
      for (int seg = 0; seg < 16; ++seg) {
        int nb = seg * 4 + 4;                  // pad makes seg=15 reads safe
        float4 B0 = a4[nb], B1 = a4[nb + 1], B2 = a4[nb + 2], B3 = a4[nb + 3];
        int i0 = seg * 4;
        CH4(A0, i0); CH4(A1, i0 + 1); CH4(A2, i0 + 2); CH4(A3, i0 + 3);
        A0 = B0; A1 = B1; A2 = B2; A3 = B3;
      }
      Tcarry = T;
      s_bg = T;
      s_term = (T <= 1e-4f) ? 1u : 0u;
    }
    __syncthreads();

    float Tpre = (t == 0) ? s_Tstart : s_Ti[t - 1];
    float w = a * Tpre;
    dsum += w * ts;
    float sc = 0.0f, app = 0.0f;
    if (w > 1e-4f) { app = 1.0f; sc = w * pv; }   // pv precomputed: no loads here
    out[OFF_W + rb + s] = w;
    out[OFF_FULL + rb + s] = sc;   // score stash (0.0 bits == final mask 0.0)
    out[OFF_INV + rb + s] = app;   // app stash (== final inv unless full)

    if (s_term) { cproc = c + 1; break; }   // uniform (read after barrier)
    __syncthreads();   // WAR: protect s_alpha/s_Ti before next chunk's writes
  }

  // zero-fill truncated tail (masks exact; |w| <= 1e-4)
  for (int s2 = cproc * 256 + t; s2 < NS; s2 += 256) {
    out[OFF_W + rb + s2] = 0.0f;
    out[OFF_FULL + rb + s2] = 0.0f;
    out[OFF_INV + rb + s2] = 0.0f;
  }

  s_red[t] = dsum;
  __syncthreads();
  for (int off = 128; off > 0; off >>= 1) {
    if (t < off) s_red[t] += s_red[t + off];
    __syncthreads();
  }
  if (t == 0) {
    out[OFF_DEPTH + r] = s_red[0];
    out[OFF_BG + r] = s_bg;
  }
}

// spin grid-barrier: valid because all TOPK_NB=256 blocks are co-resident.
// __syncthreads drains this block's vmem (atomics performed at coherent point)
// before the ticket.
__device__ __forceinline__ void gbar(unsigned* ctr) {
  __syncthreads();
  if (threadIdx.x == 0) {
    TICKET(ctr);
    while (AGLD(ctr) < (unsigned)TOPK_NB) __builtin_amdgcn_s_sleep(8);
  }
  __syncthreads();
}

// suffix-scan radix find over nbins counts already resident in sb.
// res[0]=sel bin, res[1]=count strictly above (incl base), res[2]=count >=.
// s_loc[0]=base+total. Caller must sync before entry.
__device__ void find_core(const unsigned* sb, int nbins, unsigned base,
                          unsigned* s_loc, unsigned* res, int t) {
  int C = nbins >> 8;
  unsigned csum = 0;
  int b0 = t * C;
  for (int k = 0; k < C; k++) csum += sb[b0 + k];
  s_loc[t] = csum;
  __syncthreads();
  for (int off = 1; off < 256; off <<= 1) {
    unsigned v = (t + off < 256) ? s_loc[t + off] : 0u;
    __syncthreads();
    s_loc[t] += v;
    __syncthreads();
  }
  if (t == 0) s_loc[0] += base;
  unsigned run = (t + 1 < 256) ? s_loc[t + 1] : 0u;
  for (int k = C - 1; k >= 0; k--) {
    unsigned nxt = run;
    run += sb[b0 + k];
    if (base + run >= TOPK && base + nxt < TOPK) {
      res[0] = (unsigned)(b0 + k);
      res[1] = base + nxt;
      res[2] = base + run;
    }
  }
  __syncthreads();
}

__device__ void find_in(const unsigned* __restrict__ g, int nbins, int hs,
                        unsigned base, unsigned* sb, unsigned* s_loc,
                        unsigned* res, int t) {
  for (int i = t; i < nbins; i += 256) sb[i] = AGLD(&g[(size_t)i * hs]);
  __syncthreads();
  find_core(sb, nbins, base, s_loc, res, t);
}

// 256 blocks x 256 threads. Normal path (3 gbars): P1 scan+capture+hist1 ->
// gbar -> find1 -> append sel1-bin values to Lu (agent-scope stores) -> gbar
// -> LOCAL LDS radix passes 2+3 over Lu (redundant per block, no barriers) ->
// apply -> gbar -> block0 tie patch. Fallback (bin > LCAP, uniform decision):
// proven 4-gbar global-hist path.
__global__ __launch_bounds__(256) void k_topk(
    float* __restrict__ out, unsigned* __restrict__ state,
    unsigned* __restrict__ h1, unsigned* __restrict__ h2,
    unsigned* __restrict__ h3, unsigned* __restrict__ tie,
    unsigned* __restrict__ Lu, int hs, unsigned LCAP) {
  __shared__ unsigned sh[2048];
  __shared__ unsigned s_loc[256];
  __shared__ unsigned res[3];
  __shared__ unsigned s_capu[CAPN];
  __shared__ unsigned s_capi[CAPN];
  __shared__ unsigned s_ccnt, s_ovf;
  int t = threadIdx.x;
  int lane = t & 63;
  const uint4* sc4 = (const uint4*)(out + OFF_FULL);
  unsigned tb = 0u, M = 0u;

  // ---- P1: single full scan; LDS capture + LDS hist1 ----
  for (int i = t; i < 2048; i += 256) sh[i] = 0u;
  if (t == 0) { s_ccnt = 0u; s_ovf = 0u; }
  __syncthreads();
  for (int i = blockIdx.x * 256 + t; i < NEL4; i += TOPK_NB * 256) {
    uint4 v = sc4[i];
    #pragma unroll
    for (int c = 0; c < 4; ++c) {
      unsigned u = (c == 0) ? v.x : (c == 1) ? v.y : (c == 2) ? v.z : v.w;
      if (!u) continue;
      atomicAdd(&sh[u >> 21], 1u);
      unsigned p = atomicAdd(&s_ccnt, 1u);
      if (p < CAPN) { s_capu[p] = u; s_capi[p] = 4u * (unsigned)i + (unsigned)c; }
      else s_ovf = 1u;
    }
  }
  __syncthreads();
  for (int i = t; i < 2048; i += 256) {
    unsigned v = sh[i];
    if (v) atomicAdd(&h1[(size_t)i * hs], v);
  }
  if (t == 0 && s_ovf) AGST(&state[ST_OVF], 1u);
  unsigned ccnt = (s_ccnt < CAPN) ? s_ccnt : CAPN;
  gbar(&state[ST_TK1]);
  unsigned ovf = AGLD(&state[ST_OVF]);   // uniform across blocks
  find_in(h1, 2048, hs, 0u, sh, s_loc, res, t);
  bool done = (s_loc[0] < TOPK);         // all positives selected
  unsigned sel1 = 0u, base1 = 0u, cntbin = 0u;
  if (!done) { sel1 = res[0]; base1 = res[1]; cntbin = res[2] - res[1]; }
  __syncthreads();

  if (!done && cntbin <= LCAP) {
    // ---- normal: append sel1-bin values to Lu ----
    if (!ovf) {
      for (unsigned i = t; i < ccnt; i += 256) {
        unsigned u = (i < ccnt) ? s_capu[i] : 0u;
        bool m = (u >> 21) == sel1;
        unsigned long long act = __ballot(m);
        if (m) {
          int ldr = (int)(__ffsll((unsigned long long)act) - 1);
          unsigned wb = 0;
          if (lane == ldr) wb = atomicAdd(&state[ST_LN], (unsigned)__popcll(act));
          wb = (unsigned)__shfl((int)wb, ldr);
          unsigned pos = wb + (unsigned)__popcll(act & ((1ull << lane) - 1ull));
          if (pos < LCAP) AGST(&Lu[pos], u);   // agent-scope: cross-XCD visible
        }
      }
    } else {
      for (int i = blockIdx.x * 256 + t; i < NEL4; i += TOPK_NB * 256) {
        uint4 v = sc4[i];
        #pragma unroll
        for (int c = 0; c < 4; ++c) {
          unsigned u = (c == 0) ? v.x : (c == 1) ? v.y : (c == 2) ? v.z : v.w;
          bool m = u && (u >> 21) == sel1;
          unsigned long long act = __ballot(m);
          if (m) {
            int ldr = (int)(__ffsll((unsigned long long)act) - 1);
            unsigned wb = 0;
            if (lane == ldr) wb = atomicAdd(&state[ST_LN], (unsigned)__popcll(act));
            wb = (unsigned)__shfl((int)wb, ldr);
            unsigned pos = wb + (unsigned)__popcll(act & ((1ull << lane) - 1ull));
            if (pos < LCAP) AGST(&Lu[pos], u);
          }
        }
      }
    }
    gbar(&state[ST_TK2]);
    unsigned nL = AGLD(&state[ST_LN]);   // == cntbin <= LCAP
    // ---- local pass 2 (bits 20..10) over Lu ----
    for (int i = t; i < 2048; i += 256) sh[i] = 0u;
    __syncthreads();
    for (unsigned i = t; i < nL; i += 256)
      atomicAdd(&sh[(AGLD(&Lu[i]) >> 10) & 0x7FFu], 1u);
    __syncthreads();
    find_core(sh, 2048, base1, s_loc, res, t);
    unsigned sel2 = res[0], base2 = res[1];
    __syncthreads();
    // ---- local pass 3 (bits 9..0) ----
    for (int i = t; i < 1024; i += 256) sh[i] = 0u;
    __syncthreads();
    unsigned sel12 = (sel1 << 11) | sel2;
    for (unsigned i = t; i < nL; i += 256) {
      unsigned u = AGLD(&Lu[i]);
      if ((u >> 10) == sel12) atomicAdd(&sh[u & 0x3FFu], 1u);
    }
    __syncthreads();
    find_core(sh, 1024, base2, s_loc, res, t);
    tb = (sel1 << 21) | (sel2 << 10) | res[0];
    M = TOPK - res[1];
  } else if (!done) {
    // ---- fallback: proven global-hist path (4 gbars total) ----
    for (int i = t; i < 2048; i += 256) sh[i] = 0u;
    __syncthreads();
    if (ovf) {
      for (int i = blockIdx.x * 256 + t; i < NEL4; i += TOPK_NB * 256) {
        uint4 v = sc4[i];
        if (v.x && (v.x >> 21) == sel1) atomicAdd(&sh[(v.x >> 10) & 0x7FFu], 1u);
        if (v.y && (v.y >> 21) == sel1) atomicAdd(&sh[(v.y >> 10) & 0x7FFu], 1u);
        if (v.z && (v.z >> 21) == sel1) atomicAdd(&sh[(v.z >> 10) & 0x7FFu], 1u);
        if (v.w && (v.w >> 21) == sel1) atomicAdd(&sh[(v.w >> 10) & 0x7FFu], 1u);
      }
    } else {
      for (unsigned i = t; i < ccnt; i += 256) {
        unsigned u = s_capu[i];
        if ((u >> 21) == sel1) atomicAdd(&sh[(u >> 10) & 0x7FFu], 1u);
      }
    }
    __syncthreads();
    for (int i = t; i < 2048; i += 256) {
      unsigned v = sh[i];
      if (v) atomicAdd(&h2[(size_t)i * hs], v);
    }
    gbar(&state[ST_TK2]);
    find_in(h2, 2048, hs, base1, sh, s_loc, res, t);
    unsigned sel2 = res[0], base2 = res[1];
    __syncthreads();
    for (int i = t; i < 1024; i += 256) sh[i] = 0u;
    __syncthreads();
    unsigned sel12 = (sel1 << 11) | sel2;
    if (ovf) {
      for (int i = blockIdx.x * 256 + t; i < NEL4; i += TOPK_NB * 256) {
        uint4 v = sc4[i];
        if (v.x && (v.x >> 10) == sel12) atomicAdd(&sh[v.x & 0x3FFu], 1u);
        if (v.y && (v.y >> 10) == sel12) atomicAdd(&sh[v.y & 0x3FFu], 1u);
        if (v.z && (v.z >> 10) == sel12) atomicAdd(&sh[v.z & 0x3FFu], 1u);
        if (v.w && (v.w >> 10) == sel12) atomicAdd(&sh[v.w & 0x3FFu], 1u);
      }
    } else {
      for (unsigned i = t; i < ccnt; i += 256) {
        unsigned u = s_capu[i];
        if ((u >> 10) == sel12) atomicAdd(&sh[u & 0x3FFu], 1u);
      }
    }
    __syncthreads();
    for (int i = t; i < 1024; i += 256) {
      unsigned v = sh[i];
      if (v) atomicAdd(&h3[(size_t)i * hs], v);
    }
    gbar(&state[ST_TK3]);
    find_in(h3, 1024, hs, base2, sh, s_loc, res, t);
    tb = (sel1 << 21) | (sel2 << 10) | res[0];
    M = TOPK - res[1];
  }

  // ---- apply (zero slots already hold correct 0.0) ----
  if (ovf) {
    for (int i = blockIdx.x * 256 + t; i < NEL4; i += TOPK_NB * 256) {
      uint4 v = sc4[i];
      #pragma unroll
      for (int c = 0; c < 4; ++c) {
        unsigned u = (c == 0) ? v.x : (c == 1) ? v.y : (c == 2) ? v.z : v.w;
        if (!u) continue;
        unsigned idx = 4u * (unsigned)i + (unsigned)c;
        if (tb == 0u || u > tb) {
          out[OFF_FULL + idx] = 1.0f;
          out[OFF_INV + idx] = 0.0f;
        } else if (u == tb) {
          atomicExch(&out[OFF_FULL + idx], 0.0f);
          unsigned p = atomicAdd(&state[ST_TIEN], 1u);
          if (p < TIE_CAP) atomicExch(&tie[p], idx);
        } else {
          out[OFF_FULL + idx] = 0.0f;
        }
      }
    }
  } else {
    for (unsigned i = t; i < ccnt; i += 256) {
      unsigned u = s_capu[i];
      unsigned idx = s_capi[i];
      if (tb == 0u || u > tb) {
        out[OFF_FULL + idx] = 1.0f;
        out[OFF_INV + idx] = 0.0f;
      } else if (u == tb) {
        atomicExch(&out[OFF_FULL + idx], 0.0f);   // coherent: patch may overwrite
        unsigned p = atomicAdd(&state[ST_TIEN], 1u);
        if (p < TIE_CAP) atomicExch(&tie[p], idx);
      } else {
        out[OFF_FULL + idx] = 0.0f;
      }
    }
  }
  gbar(&state[ST_TK4]);
  // tie patch: first M ties in flat-index order become full
  if (blockIdx.x == 0 && t == 0 && tb != 0u) {
    unsigned ntie = AGLD(&state[ST_TIEN]);
    if (ntie > TIE_CAP) ntie = TIE_CAP;
    unsigned m = M;
    if (m > ntie) m = ntie;
    for (unsigned k = 0; k < m; k++) {
      unsigned bi = k, bv = AGLD(&tie[k]);
      for (unsigned j = k + 1; j < ntie; j++) {
        unsigned v = AGLD(&tie[j]);
        if (v < bv) { bv = v; bi = j; }
      }
      unsigned tk = AGLD(&tie[k]);
      AGST(&tie[bi], tk);
      AGST(&tie[k], bv);
      atomicExch(&out[OFF_FULL + bv], 1.0f);
      atomicExch(&out[OFF_INV + bv], 0.0f);
    }
  }
}

extern "C" void kernel_launch(void* const* d_in, const int* in_sizes, int n_in,
                              void* d_out, int out_size, void* d_ws, size_t ws_size,
                              hipStream_t stream) {
  const float* ro = (const float*)d_in[0];
  const float* rd = (const float*)d_in[1];
  const float* dens = (const float*)d_in[2];
  const float* prb = (const float*)d_in[3];
  const float* alpv = (const float*)d_in[4];
  float* out = (float*)d_out;
  unsigned* ws = (unsigned*)d_ws;

  // hist bin stride (uints): 16 => 64B/bin spreads hot-bin merge atomics
  // across cache lines (round-8/9 contention lesson). Shrink if ws is small,
  // keeping room for the Lu tie-bin list.
  size_t tu = ws_size / 4;
  int hs = 16;
  long long lcap = (long long)tu - (16 + (long long)(2048 + 2048 + 1024) * hs + TIE_CAP);
  if (lcap < 4096) {
    hs = 1;
    lcap = (long long)tu - (16 + 5120 + TIE_CAP);
  }
  if (lcap < 0) lcap = 0;
  unsigned LCAP = (unsigned)((lcap > (1 << 20)) ? (1 << 20) : lcap);
  unsigned* h1 = ws + 16;
  unsigned* h2 = h1 + (size_t)2048 * hs;
  unsigned* h3 = h2 + (size_t)2048 * hs;
  unsigned* tie = h3 + (size_t)1024 * hs;
  unsigned* Lu = tie + TIE_CAP;
  size_t zero_uints = 16 + (size_t)(2048 + 2048 + 1024) * hs;

  hipMemsetAsync(ws, 0, zero_uints * sizeof(unsigned), stream);
  k_march<<<NRAYS, 256, 0, stream>>>(ro, rd, dens, prb, alpv, out);
  k_topk<<<TOPK_NB, 256, 0, stream>>>(out, ws, h1, h2, h3, tie, Lu, hs, LCAP);
}

// Round 13
// 104.864 us; speedup vs baseline: 1.2083x; 1.2083x over previous
//
#include <hip/hip_runtime.h>
#include <math.h>

#pragma clang fp contract(off)

#define NRAYS 4096
#define NS 512
#define NEL (NRAYS * NS)          // 2097152
#define NEL4 (NEL / 4)            // 524288 uint4
#define TOPK 4000u
#define TOPK_NB 256
#define CAPN 5120                 // per-block LDS capture capacity

// d_out layout (floats), concatenated in reference return order
#define OFF_W     ((size_t)0)
#define OFF_BG    ((size_t)2097152)
#define OFF_DEPTH ((size_t)2101248)
#define OFF_FULL  ((size_t)2105344)
#define OFF_INV   ((size_t)4202496)

// ws state slots (uints)
#define ST_TIEN  6
#define ST_TK1   8
#define ST_TK2   9
#define ST_TK3   10
#define ST_TK4   11
#define ST_OVF   12
#define ST_LN    13
#define TIE_CAP  8192u

#define AGLD(p) __hip_atomic_load((p), __ATOMIC_RELAXED, __HIP_MEMORY_SCOPE_AGENT)
#define AGST(p, v) __hip_atomic_store((p), (v), __ATOMIC_RELAXED, __HIP_MEMORY_SCOPE_AGENT)
#define TICKET(p) __hip_atomic_fetch_add((p), 1u, __ATOMIC_RELAXED, __HIP_MEMORY_SCOPE_AGENT)

__device__ __forceinline__ float tri_sample(const float* __restrict__ vol, int R,
                                            float cx, float cy, float cz) {
  #pragma clang fp contract(off)
  float c0 = fminf(fmaxf(cx, -1.0f), 1.0f);
  float c1 = fminf(fmaxf(cy, -1.0f), 1.0f);
  float c2 = fminf(fmaxf(cz, -1.0f), 1.0f);
  float fR = (float)(R - 1);
  float x = (c0 + 1.0f) * 0.5f * fR;
  float y = (c1 + 1.0f) * 0.5f * fR;
  float z = (c2 + 1.0f) * 0.5f * fR;
  float xf = fminf(fmaxf(floorf(x), 0.0f), (float)(R - 2));
  float yf = fminf(fmaxf(floorf(y), 0.0f), (float)(R - 2));
  float zf = fminf(fmaxf(floorf(z), 0.0f), (float)(R - 2));
  int x0 = (int)xf, y0 = (int)yf, z0 = (int)zf;
  float xd = x - xf, yd = y - yf, zd = z - zf;
  const float* p = vol + ((size_t)z0 * R + (size_t)y0) * R + (size_t)x0;
  float c000 = p[0], c001 = p[1];
  float c010 = p[R], c011 = p[R + 1];
  const float* q = p + (size_t)R * R;
  float c100 = q[0], c101 = q[1];
  float c110 = q[R], c111 = q[R + 1];
  float omx = 1.0f - xd, omy = 1.0f - yd, omz = 1.0f - zd;
  float c00 = c000 * omx + c001 * xd;
  float c01 = c010 * omx + c011 * xd;
  float c10 = c100 * omx + c101 * xd;
  float c11 = c110 * omx + c111 * xd;
  float a0 = c00 * omy + c01 * yd;
  float a1 = c10 * omy + c11 * yd;
  return a0 * omz + a1 * zd;
}

// 4 exact left-to-right chain steps; stores inclusive products as one float4.
#define CH4(V, IDX)                                        \
  {                                                        \
    float t0_ = T * ((1.0f - (V).x) + 1e-10f);             \
    float t1_ = t0_ * ((1.0f - (V).y) + 1e-10f);           \
    float t2_ = t1_ * ((1.0f - (V).z) + 1e-10f);           \
    float t3_ = t2_ * ((1.0f - (V).w) + 1e-10f);           \
    Ti4[IDX] = make_float4(t0_, t1_, t2_, t3_);            \
    T = t3_;                                               \
  }

// Round-11 march (measured 56us): block per ray, 2 chunks of 256 samples, all
// alpha+density gathers in parallel; prob gathered GATED in phase 2 (only ~7%
// of samples pass w>1e-4 — round-12 showed unconditional prob costs +75MB/+23us).
// t0-only pipelined cumprod, bit-exact numpy left-to-right rounding. Chunk-end
// early termination (T<=1e-4): processed chunks bit-exact; skipped samples have
// ref-w <= 1e-4 so mask bits exact, |depth err| <= ~7e-4 (threshold 4.4e-2).
// ZERO global atomics (round-8/9 lesson: hot-line atomics cost ~250us).
__global__ __launch_bounds__(256) void k_march(
    const float* __restrict__ ro, const float* __restrict__ rd,
    const float* __restrict__ dens, const float* __restrict__ prb,
    const float* __restrict__ alpv, float* __restrict__ out) {
  #pragma clang fp contract(off)
  const float STEP = (float)(3.0 * 1.7320508075688772 / 512.0);
  const float DIST = (float)((3.0 * 1.7320508075688772 / 512.0) * 25.0);
  const float INVG = 2.0f / 3.0f;
  int r = blockIdx.x;
  int t = threadIdx.x;
  __shared__ __align__(16) float s_alpha[272];   // 256 + 16 pad (prefetch overrun)
  __shared__ __align__(16) float s_Ti[256];      // inclusive products for chunk
  __shared__ float s_red[256];
  __shared__ float s_Tstart, s_bg;
  __shared__ unsigned s_term;

  float ox = ro[r * 3 + 0], oy = ro[r * 3 + 1], oz = ro[r * 3 + 2];
  float dx = rd[r * 3 + 0], dy = rd[r * 3 + 1], dz = rd[r * 3 + 2];
  float vx = (dx == 0.0f) ? 1e-6f : dx;
  float vy = (dy == 0.0f) ? 1e-6f : dy;
  float vz = (dz == 0.0f) ? 1e-6f : dz;
  float tmin;
  {
    float rax = (1.5f - ox) / vx, rbx = (-1.5f - ox) / vx;
    float ray = (1.5f - oy) / vy, rby = (-1.5f - oy) / vy;
    float raz = (1.5f - oz) / vz, rbz = (-1.5f - oz) / vz;
    float m0 = fminf(rax, rbx), m1 = fminf(ray, rby), m2 = fminf(raz, rbz);
    tmin = fmaxf(fmaxf(m0, m1), m2);
    tmin = fminf(fmaxf(tmin, 2.0f), 6.0f);
  }

  unsigned rb = (unsigned)r * NS;
  float Tcarry = 1.0f;     // meaningful on t0 only
  float dsum = 0.0f;
  int cproc = 2;

  for (int c = 0; c < 2; ++c) {
    int s = c * 256 + t;
    float ts = tmin + STEP * (float)s;
    float px = ox + dx * ts;
    float py = oy + dy * ts;
    float pz = oz + dz * ts;
    bool inb = !((-1.5f > px) || (px > 1.5f) || (-1.5f > py) || (py > 1.5f) ||
                 (-1.5f > pz) || (pz > 1.5f));
    float a = 0.0f;
    float nx = 0.0f, ny = 0.0f, nz = 0.0f;
    if (inb) {
      nx = (px + 1.5f) * INVG - 1.0f;
      ny = (py + 1.5f) * INVG - 1.0f;
      nz = (pz + 1.5f) * INVG - 1.0f;
      float al = tri_sample(alpv, 128, nx, ny, nz);
      float feat = tri_sample(dens, 256, nx, ny, nz);  // independent chains overlap
      if (al > 0.001f) {
        float xx = feat + (-10.0f);
        float sp = fmaxf(xx, 0.0f) + log1pf(expf(-fabsf(xx)));
        a = 1.0f - expf(-(sp * DIST));
      }
    }
    s_alpha[t] = a;
    __syncthreads();

    // t0 pipelined serial cumprod: prefetch segment k+1 while chaining seg k.
    if (t == 0) {
      s_Tstart = Tcarry;
      float T = Tcarry;
      const float4* a4 = (const float4*)s_alpha;
      float4* Ti4 = (float4*)s_Ti;
      float4 A0 = a4[0], A1 = a4[1], A2 = a4[2], A3 = a4[3];
      for (int seg = 0; seg < 16; ++seg) {
        int nb = seg * 4 + 4;                  // pad makes seg=15 reads safe
        float4 B0 = a4[nb], B1 = a4[nb + 1], B2 = a4[nb + 2], B3 = a4[nb + 3];
        int i0 = seg * 4;
        CH4(A0, i0); CH4(A1, i0 + 1); CH4(A2, i0 + 2); CH4(A3, i0 + 3);
        A0 = B0; A1 = B1; A2 = B2; A3 = B3;
      }
      Tcarry = T;
      s_bg = T;
      s_term = (T <= 1e-4f) ? 1u : 0u;
    }
    __syncthreads();

    float Tpre = (t == 0) ? s_Tstart : s_Ti[t - 1];
    float w = a * Tpre;
    dsum += w * ts;
    float sc = 0.0f, app = 0.0f;
    if (w > 1e-4f) {
      app = 1.0f;
      float pv = tri_sample(prb, 256, nx, ny, nz);
      sc = w * pv;
    }
    out[OFF_W + rb + s] = w;
    out[OFF_FULL + rb + s] = sc;   // score stash (0.0 bits == final mask 0.0)
    out[OFF_INV + rb + s] = app;   // app stash (== final inv unless full)

    if (s_term) { cproc = c + 1; break; }   // uniform (read after barrier)
    __syncthreads();   // WAR: protect s_alpha/s_Ti before next chunk's writes
  }

  // zero-fill truncated tail (masks exact; |w| <= 1e-4)
  for (int s2 = cproc * 256 + t; s2 < NS; s2 += 256) {
    out[OFF_W + rb + s2] = 0.0f;
    out[OFF_FULL + rb + s2] = 0.0f;
    out[OFF_INV + rb + s2] = 0.0f;
  }

  s_red[t] = dsum;
  __syncthreads();
  for (int off = 128; off > 0; off >>= 1) {
    if (t < off) s_red[t] += s_red[t + off];
    __syncthreads();
  }
  if (t == 0) {
    out[OFF_DEPTH + r] = s_red[0];
    out[OFF_BG + r] = s_bg;
  }
}

// spin grid-barrier: valid because all TOPK_NB=256 blocks are co-resident.
// __syncthreads drains this block's vmem (atomics performed at coherent point)
// before the ticket.
__device__ __forceinline__ void gbar(unsigned* ctr) {
  __syncthreads();
  if (threadIdx.x == 0) {
    TICKET(ctr);
    while (AGLD(ctr) < (unsigned)TOPK_NB) __builtin_amdgcn_s_sleep(8);
  }
  __syncthreads();
}

// suffix-scan radix find over nbins counts already resident in sb.
// res[0]=sel bin, res[1]=count strictly above (incl base), res[2]=count >=.
// s_loc[0]=base+total. Caller must sync before entry.
__device__ void find_core(const unsigned* sb, int nbins, unsigned base,
                          unsigned* s_loc, unsigned* res, int t) {
  int C = nbins >> 8;
  unsigned csum = 0;
  int b0 = t * C;
  for (int k = 0; k < C; k++) csum += sb[b0 + k];
  s_loc[t] = csum;
  __syncthreads();
  for (int off = 1; off < 256; off <<= 1) {
    unsigned v = (t + off < 256) ? s_loc[t + off] : 0u;
    __syncthreads();
    s_loc[t] += v;
    __syncthreads();
  }
  if (t == 0) s_loc[0] += base;
  unsigned run = (t + 1 < 256) ? s_loc[t + 1] : 0u;
  for (int k = C - 1; k >= 0; k--) {
    unsigned nxt = run;
    run += sb[b0 + k];
    if (base + run >= TOPK && base + nxt < TOPK) {
      res[0] = (unsigned)(b0 + k);
      res[1] = base + nxt;
      res[2] = base + run;
    }
  }
  __syncthreads();
}

__device__ void find_in(const unsigned* __restrict__ g, int nbins, int hs,
                        unsigned base, unsigned* sb, unsigned* s_loc,
                        unsigned* res, int t) {
  for (int i = t; i < nbins; i += 256) sb[i] = AGLD(&g[(size_t)i * hs]);
  __syncthreads();
  find_core(sb, nbins, base, s_loc, res, t);
}

// 256 blocks x 256 threads. Normal path (3 gbars): P1 scan+capture+hist1 ->
// gbar -> find1 -> append sel1-bin values to Lu (agent-scope stores) -> gbar
// -> LOCAL LDS radix passes 2+3 over Lu (redundant per block, no barriers) ->
// apply -> gbar -> block0 tie patch. Fallback (bin > LCAP, uniform decision):
// proven 4-gbar global-hist path.
__global__ __launch_bounds__(256) void k_topk(
    float* __restrict__ out, unsigned* __restrict__ state,
    unsigned* __restrict__ h1, unsigned* __restrict__ h2,
    unsigned* __restrict__ h3, unsigned* __restrict__ tie,
    unsigned* __restrict__ Lu, int hs, unsigned LCAP) {
  __shared__ unsigned sh[2048];
  __shared__ unsigned s_loc[256];
  __shared__ unsigned res[3];
  __shared__ unsigned s_capu[CAPN];
  __shared__ unsigned s_capi[CAPN];
  __shared__ unsigned s_ccnt, s_ovf;
  int t = threadIdx.x;
  int lane = t & 63;
  const uint4* sc4 = (const uint4*)(out + OFF_FULL);
  unsigned tb = 0u, M = 0u;

  // ---- P1: single full scan; LDS capture + LDS hist1 ----
  for (int i = t; i < 2048; i += 256) sh[i] = 0u;
  if (t == 0) { s_ccnt = 0u; s_ovf = 0u; }
  __syncthreads();
  for (int i = blockIdx.x * 256 + t; i < NEL4; i += TOPK_NB * 256) {
    uint4 v = sc4[i];
    #pragma unroll
    for (int c = 0; c < 4; ++c) {
      unsigned u = (c == 0) ? v.x : (c == 1) ? v.y : (c == 2) ? v.z : v.w;
      if (!u) continue;
      atomicAdd(&sh[u >> 21], 1u);
      unsigned p = atomicAdd(&s_ccnt, 1u);
      if (p < CAPN) { s_capu[p] = u; s_capi[p] = 4u * (unsigned)i + (unsigned)c; }
      else s_ovf = 1u;
    }
  }
  __syncthreads();
  for (int i = t; i < 2048; i += 256) {
    unsigned v = sh[i];
    if (v) atomicAdd(&h1[(size_t)i * hs], v);
  }
  if (t == 0 && s_ovf) AGST(&state[ST_OVF], 1u);
  unsigned ccnt = (s_ccnt < CAPN) ? s_ccnt : CAPN;
  gbar(&state[ST_TK1]);
  unsigned ovf = AGLD(&state[ST_OVF]);   // uniform across blocks
  find_in(h1, 2048, hs, 0u, sh, s_loc, res, t);
  bool done = (s_loc[0] < TOPK);         // all positives selected
  unsigned sel1 = 0u, base1 = 0u, cntbin = 0u;
  if (!done) { sel1 = res[0]; base1 = res[1]; cntbin = res[2] - res[1]; }
  __syncthreads();

  if (!done && cntbin <= LCAP) {
    // ---- normal: append sel1-bin values to Lu ----
    if (!ovf) {
      for (unsigned i = t; i < ccnt; i += 256) {
        unsigned u = s_capu[i];
        bool m = (u >> 21) == sel1;
        unsigned long long act = __ballot(m);
        if (m) {
          int ldr = (int)(__ffsll((unsigned long long)act) - 1);
          unsigned wb = 0;
          if (lane == ldr) wb = atomicAdd(&state[ST_LN], (unsigned)__popcll(act));
          wb = (unsigned)__shfl((int)wb, ldr);
          unsigned pos = wb + (unsigned)__popcll(act & ((1ull << lane) - 1ull));
          if (pos < LCAP) AGST(&Lu[pos], u);   // agent-scope: cross-XCD visible
        }
      }
    } else {
      for (int i = blockIdx.x * 256 + t; i < NEL4; i += TOPK_NB * 256) {
        uint4 v = sc4[i];
        #pragma unroll
        for (int c = 0; c < 4; ++c) {
          unsigned u = (c == 0) ? v.x : (c == 1) ? v.y : (c == 2) ? v.z : v.w;
          bool m = u && (u >> 21) == sel1;
          unsigned long long act = __ballot(m);
          if (m) {
            int ldr = (int)(__ffsll((unsigned long long)act) - 1);
            unsigned wb = 0;
            if (lane == ldr) wb = atomicAdd(&state[ST_LN], (unsigned)__popcll(act));
            wb = (unsigned)__shfl((int)wb, ldr);
            unsigned pos = wb + (unsigned)__popcll(act & ((1ull << lane) - 1ull));
            if (pos < LCAP) AGST(&Lu[pos], u);
          }
        }
      }
    }
    gbar(&state[ST_TK2]);
    unsigned nL = AGLD(&state[ST_LN]);   // == cntbin <= LCAP
    // ---- local pass 2 (bits 20..10) over Lu ----
    for (int i = t; i < 2048; i += 256) sh[i] = 0u;
    __syncthreads();
    for (unsigned i = t; i < nL; i += 256)
      atomicAdd(&sh[(AGLD(&Lu[i]) >> 10) & 0x7FFu], 1u);
    __syncthreads();
    find_core(sh, 2048, base1, s_loc, res, t);
    unsigned sel2 = res[0], base2 = res[1];
    __syncthreads();
    // ---- local pass 3 (bits 9..0) ----
    for (int i = t; i < 1024; i += 256) sh[i] = 0u;
    __syncthreads();
    unsigned sel12 = (sel1 << 11) | sel2;
    for (unsigned i = t; i < nL; i += 256) {
      unsigned u = AGLD(&Lu[i]);
      if ((u >> 10) == sel12) atomicAdd(&sh[u & 0x3FFu], 1u);
    }
    __syncthreads();
    find_core(sh, 1024, base2, s_loc, res, t);
    tb = (sel1 << 21) | (sel2 << 10) | res[0];
    M = TOPK - res[1];
  } else if (!done) {
    // ---- fallback: proven global-hist path (4 gbars total) ----
    for (int i = t; i < 2048; i += 256) sh[i] = 0u;
    __syncthreads();
    if (ovf) {
      for (int i = blockIdx.x * 256 + t; i < NEL4; i += TOPK_NB * 256) {
        uint4 v = sc4[i];
        if (v.x && (v.x >> 21) == sel1) atomicAdd(&sh[(v.x >> 10) & 0x7FFu], 1u);
        if (v.y && (v.y >> 21) == sel1) atomicAdd(&sh[(v.y >> 10) & 0x7FFu], 1u);
        if (v.z && (v.z >> 21) == sel1) atomicAdd(&sh[(v.z >> 10) & 0x7FFu], 1u);
        if (v.w && (v.w >> 21) == sel1) atomicAdd(&sh[(v.w >> 10) & 0x7FFu], 1u);
      }
    } else {
      for (unsigned i = t; i < ccnt; i += 256) {
        unsigned u = s_capu[i];
        if ((u >> 21) == sel1) atomicAdd(&sh[(u >> 10) & 0x7FFu], 1u);
      }
    }
    __syncthreads();
    for (int i = t; i < 2048; i += 256) {
      unsigned v = sh[i];
      if (v) atomicAdd(&h2[(size_t)i * hs], v);
    }
    gbar(&state[ST_TK2]);
    find_in(h2, 2048, hs, base1, sh, s_loc, res, t);
    unsigned sel2 = res[0], base2 = res[1];
    __syncthreads();
    for (int i = t; i < 1024; i += 256) sh[i] = 0u;
    __syncthreads();
    unsigned sel12 = (sel1 << 11) | sel2;
    if (ovf) {
      for (int i = blockIdx.x * 256 + t; i < NEL4; i += TOPK_NB * 256) {
        uint4 v = sc4[i];
        if (v.x && (v.x >> 10) == sel12) atomicAdd(&sh[v.x & 0x3FFu], 1u);
        if (v.y && (v.y >> 10) == sel12) atomicAdd(&sh[v.y & 0x3FFu], 1u);
        if (v.z && (v.z >> 10) == sel12) atomicAdd(&sh[v.z & 0x3FFu], 1u);
        if (v.w && (v.w >> 10) == sel12) atomicAdd(&sh[v.w & 0x3FFu], 1u);
      }
    } else {
      for (unsigned i = t; i < ccnt; i += 256) {
        unsigned u = s_capu[i];
        if ((u >> 10) == sel12) atomicAdd(&sh[u & 0x3FFu], 1u);
      }
    }
    __syncthreads();
    for (int i = t; i < 1024; i += 256) {
      unsigned v = sh[i];
      if (v) atomicAdd(&h3[(size_t)i * hs], v);
    }
    gbar(&state[ST_TK3]);
    find_in(h3, 1024, hs, base2, sh, s_loc, res, t);
    tb = (sel1 << 21) | (sel2 << 10) | res[0];
    M = TOPK - res[1];
  }

  // ---- apply (zero slots already hold correct 0.0) ----
  if (ovf) {
    for (int i = blockIdx.x * 256 + t; i < NEL4; i += TOPK_NB * 256) {
      uint4 v = sc4[i];
      #pragma unroll
      for (int c = 0; c < 4; ++c) {
        unsigned u = (c == 0) ? v.x : (c == 1) ? v.y : (c == 2) ? v.z : v.w;
        if (!u) continue;
        unsigned idx = 4u * (unsigned)i + (unsigned)c;
        if (tb == 0u || u > tb) {
          out[OFF_FULL + idx] = 1.0f;
          out[OFF_INV + idx] = 0.0f;
        } else if (u == tb) {
          atomicExch(&out[OFF_FULL + idx], 0.0f);
          unsigned p = atomicAdd(&state[ST_TIEN], 1u);
          if (p < TIE_CAP) atomicExch(&tie[p], idx);
        } else {
          out[OFF_FULL + idx] = 0.0f;
        }
      }
    }
  } else {
    for (unsigned i = t; i < ccnt; i += 256) {
      unsigned u = s_capu[i];
      unsigned idx = s_capi[i];
      if (tb == 0u || u > tb) {
        out[OFF_FULL + idx] = 1.0f;
        out[OFF_INV + idx] = 0.0f;
      } else if (u == tb) {
        atomicExch(&out[OFF_FULL + idx], 0.0f);   // coherent: patch may overwrite
        unsigned p = atomicAdd(&state[ST_TIEN], 1u);
        if (p < TIE_CAP) atomicExch(&tie[p], idx);
      } else {
        out[OFF_FULL + idx] = 0.0f;
      }
    }
  }
  gbar(&state[ST_TK4]);
  // tie patch: first M ties in flat-index order become full
  if (blockIdx.x == 0 && t == 0 && tb != 0u) {
    unsigned ntie = AGLD(&state[ST_TIEN]);
    if (ntie > TIE_CAP) ntie = TIE_CAP;
    unsigned m = M;
    if (m > ntie) m = ntie;
    for (unsigned k = 0; k < m; k++) {
      unsigned bi = k, bv = AGLD(&tie[k]);
      for (unsigned j = k + 1; j < ntie; j++) {
        unsigned v = AGLD(&tie[j]);
        if (v < bv) { bv = v; bi = j; }
      }
      unsigned tk = AGLD(&tie[k]);
      AGST(&tie[bi], tk);
      AGST(&tie[k], bv);
      atomicExch(&out[OFF_FULL + bv], 1.0f);
      atomicExch(&out[OFF_INV + bv], 0.0f);
    }
  }
}

extern "C" void kernel_launch(void* const* d_in, const int* in_sizes, int n_in,
                              void* d_out, int out_size, void* d_ws, size_t ws_size,
                              hipStream_t stream) {
  const float* ro = (const float*)d_in[0];
  const float* rd = (const float*)d_in[1];
  const float* dens = (const float*)d_in[2];
  const float* prb = (const float*)d_in[3];
  const float* alpv = (const float*)d_in[4];
  float* out = (float*)d_out;
  unsigned* ws = (unsigned*)d_ws;

  // hist bin stride (uints): 16 => 64B/bin spreads hot-bin merge atomics
  // across cache lines (round-8/9 contention lesson). Shrink if ws is small,
  // keeping room for the Lu tie-bin list.
  size_t tu = ws_size / 4;
  int hs = 16;
  long long lcap = (long long)tu - (16 + (long long)(2048 + 2048 + 1024) * hs + TIE_CAP);
  if (lcap < 4096) {
    hs = 1;
    lcap = (long long)tu - (16 + 5120 + TIE_CAP);
  }
  if (lcap < 0) lcap = 0;
  unsigned LCAP = (unsigned)((lcap > (1 << 20)) ? (1 << 20) : lcap);
  unsigned* h1 = ws + 16;
  unsigned* h2 = h1 + (size_t)2048 * hs;
  unsigned* h3 = h2 + (size_t)2048 * hs;
  unsigned* tie = h3 + (size_t)1024 * hs;
  unsigned* Lu = tie + TIE_CAP;
  size_t zero_uints = 16 + (size_t)(2048 + 2048 + 1024) * hs;

  hipMemsetAsync(ws, 0, zero_uints * sizeof(unsigned), stream);
  k_march<<<NRAYS, 256, 0, stream>>>(ro, rd, dens, prb, alpv, out);
  k_topk<<<TOPK_NB, 256, 0, stream>>>(out, ws, h1, h2, h3, tie, Lu, hs, LCAP);
}

// Round 14
// 91.428 us; speedup vs baseline: 1.3858x; 1.1470x over previous
//
#include <hip/hip_runtime.h>
#include <math.h>

#pragma clang fp contract(off)

#define NRAYS 4096
#define NS 512
#define NEL (NRAYS * NS)          // 2097152
#define NEL4 (NEL / 4)            // 524288 uint4
#define TOPK 4000u
#define TOPK_NB 128
#define CAPN 5120                 // per-block LDS capture capacity

// d_out layout (floats), concatenated in reference return order
#define OFF_W     ((size_t)0)
#define OFF_BG    ((size_t)2097152)
#define OFF_DEPTH ((size_t)2101248)
#define OFF_FULL  ((size_t)2105344)
#define OFF_INV   ((size_t)4202496)

// ws state slots (uints)
#define ST_TIEN  6
#define ST_TK1   8
#define ST_TK2   9
#define ST_TK3   10
#define ST_TK4   11
#define ST_OVF   12
#define TIE_CAP  8192u

#define AGLD(p) __hip_atomic_load((p), __ATOMIC_RELAXED, __HIP_MEMORY_SCOPE_AGENT)
#define AGST(p, v) __hip_atomic_store((p), (v), __ATOMIC_RELAXED, __HIP_MEMORY_SCOPE_AGENT)
#define TICKET(p) __hip_atomic_fetch_add((p), 1u, __ATOMIC_RELAXED, __HIP_MEMORY_SCOPE_AGENT)

__device__ __forceinline__ float tri_sample(const float* __restrict__ vol, int R,
                                            float cx, float cy, float cz) {
  #pragma clang fp contract(off)
  float c0 = fminf(fmaxf(cx, -1.0f), 1.0f);
  float c1 = fminf(fmaxf(cy, -1.0f), 1.0f);
  float c2 = fminf(fmaxf(cz, -1.0f), 1.0f);
  float fR = (float)(R - 1);
  float x = (c0 + 1.0f) * 0.5f * fR;
  float y = (c1 + 1.0f) * 0.5f * fR;
  float z = (c2 + 1.0f) * 0.5f * fR;
  float xf = fminf(fmaxf(floorf(x), 0.0f), (float)(R - 2));
  float yf = fminf(fmaxf(floorf(y), 0.0f), (float)(R - 2));
  float zf = fminf(fmaxf(floorf(z), 0.0f), (float)(R - 2));
  int x0 = (int)xf, y0 = (int)yf, z0 = (int)zf;
  float xd = x - xf, yd = y - yf, zd = z - zf;
  const float* p = vol + ((size_t)z0 * R + (size_t)y0) * R + (size_t)x0;
  float c000 = p[0], c001 = p[1];
  float c010 = p[R], c011 = p[R + 1];
  const float* q = p + (size_t)R * R;
  float c100 = q[0], c101 = q[1];
  float c110 = q[R], c111 = q[R + 1];
  float omx = 1.0f - xd, omy = 1.0f - yd, omz = 1.0f - zd;
  float c00 = c000 * omx + c001 * xd;
  float c01 = c010 * omx + c011 * xd;
  float c10 = c100 * omx + c101 * xd;
  float c11 = c110 * omx + c111 * xd;
  float a0 = c00 * omy + c01 * yd;
  float a1 = c10 * omy + c11 * yd;
  return a0 * omz + a1 * zd;
}

// 4 exact left-to-right chain steps; stores inclusive products as one float4.
#define CH4(V, IDX)                                        \
  {                                                        \
    float t0_ = T * ((1.0f - (V).x) + 1e-10f);             \
    float t1_ = t0_ * ((1.0f - (V).y) + 1e-10f);           \
    float t2_ = t1_ * ((1.0f - (V).z) + 1e-10f);           \
    float t3_ = t2_ * ((1.0f - (V).w) + 1e-10f);           \
    Ti4[IDX] = make_float4(t0_, t1_, t2_, t3_);            \
    T = t3_;                                               \
  }

// Round-11 march (measured 56us, stable over 5 rounds): block per ray, 2
// chunks of 256 samples, all alpha+density gathers in parallel; prob gathered
// GATED in phase 2 (round-12: unconditional prob costs +75MB/+23us). t0-only
// pipelined cumprod, bit-exact numpy left-to-right rounding. Chunk-end early
// termination (T<=1e-4): processed chunks bit-exact; skipped samples have
// ref-w <= 1e-4 so mask bits exact, |depth err| <= ~7e-4 (threshold 4.4e-2).
// ZERO global atomics (round-8/9 lesson: hot-line atomics cost ~250us).
__global__ __launch_bounds__(256) void k_march(
    const float* __restrict__ ro, const float* __restrict__ rd,
    const float* __restrict__ dens, const float* __restrict__ prb,
    const float* __restrict__ alpv, float* __restrict__ out) {
  #pragma clang fp contract(off)
  const float STEP = (float)(3.0 * 1.7320508075688772 / 512.0);
  const float DIST = (float)((3.0 * 1.7320508075688772 / 512.0) * 25.0);
  const float INVG = 2.0f / 3.0f;
  int r = blockIdx.x;
  int t = threadIdx.x;
  __shared__ __align__(16) float s_alpha[272];   // 256 + 16 pad (prefetch overrun)
  __shared__ __align__(16) float s_Ti[256];      // inclusive products for chunk
  __shared__ float s_red[256];
  __shared__ float s_Tstart, s_bg;
  __shared__ unsigned s_term;

  float ox = ro[r * 3 + 0], oy = ro[r * 3 + 1], oz = ro[r * 3 + 2];
  float dx = rd[r * 3 + 0], dy = rd[r * 3 + 1], dz = rd[r * 3 + 2];
  float vx = (dx == 0.0f) ? 1e-6f : dx;
  float vy = (dy == 0.0f) ? 1e-6f : dy;
  float vz = (dz == 0.0f) ? 1e-6f : dz;
  float tmin;
  {
    float rax = (1.5f - ox) / vx, rbx = (-1.5f - ox) / vx;
    float ray = (1.5f - oy) / vy, rby = (-1.5f - oy) / vy;
    float raz = (1.5f - oz) / vz, rbz = (-1.5f - oz) / vz;
    float m0 = fminf(rax, rbx), m1 = fminf(ray, rby), m2 = fminf(raz, rbz);
    tmin = fmaxf(fmaxf(m0, m1), m2);
    tmin = fminf(fmaxf(tmin, 2.0f), 6.0f);
  }

  unsigned rb = (unsigned)r * NS;
  float Tcarry = 1.0f;     // meaningful on t0 only
  float dsum = 0.0f;
  int cproc = 2;

  for (int c = 0; c < 2; ++c) {
    int s = c * 256 + t;
    float ts = tmin + STEP * (float)s;
    float px = ox + dx * ts;
    float py = oy + dy * ts;
    float pz = oz + dz * ts;
    bool inb = !((-1.5f > px) || (px > 1.5f) || (-1.5f > py) || (py > 1.5f) ||
                 (-1.5f > pz) || (pz > 1.5f));
    float a = 0.0f;
    float nx = 0.0f, ny = 0.0f, nz = 0.0f;
    if (inb) {
      nx = (px + 1.5f) * INVG - 1.0f;
      ny = (py + 1.5f) * INVG - 1.0f;
      nz = (pz + 1.5f) * INVG - 1.0f;
      float al = tri_sample(alpv, 128, nx, ny, nz);
      float feat = tri_sample(dens, 256, nx, ny, nz);  // independent chains overlap
      if (al > 0.001f) {
        float xx = feat + (-10.0f);
        float sp = fmaxf(xx, 0.0f) + log1pf(expf(-fabsf(xx)));
        a = 1.0f - expf(-(sp * DIST));
      }
    }
    s_alpha[t] = a;
    __syncthreads();

    // t0 pipelined serial cumprod: prefetch segment k+1 while chaining seg k.
    if (t == 0) {
      s_Tstart = Tcarry;
      float T = Tcarry;
      const float4* a4 = (const float4*)s_alpha;
      float4* Ti4 = (float4*)s_Ti;
      float4 A0 = a4[0], A1 = a4[1], A2 = a4[2], A3 = a4[3];
      for (int seg = 0; seg < 16; ++seg) {
        int nb = seg * 4 + 4;                  // pad makes seg=15 reads safe
        float4 B0 = a4[nb], B1 = a4[nb + 1], B2 = a4[nb + 2], B3 = a4[nb + 3];
        int i0 = seg * 4;
        CH4(A0, i0); CH4(A1, i0 + 1); CH4(A2, i0 + 2); CH4(A3, i0 + 3);
        A0 = B0; A1 = B1; A2 = B2; A3 = B3;
      }
      Tcarry = T;
      s_bg = T;
      s_term = (T <= 1e-4f) ? 1u : 0u;
    }
    __syncthreads();

    float Tpre = (t == 0) ? s_Tstart : s_Ti[t - 1];
    float w = a * Tpre;
    dsum += w * ts;
    float sc = 0.0f, app = 0.0f;
    if (w > 1e-4f) {
      app = 1.0f;
      float pv = tri_sample(prb, 256, nx, ny, nz);
      sc = w * pv;
    }
    out[OFF_W + rb + s] = w;
    out[OFF_FULL + rb + s] = sc;   // score stash (0.0 bits == final mask 0.0)
    out[OFF_INV + rb + s] = app;   // app stash (== final inv unless full)

    if (s_term) { cproc = c + 1; break; }   // uniform (read after barrier)
    __syncthreads();   // WAR: protect s_alpha/s_Ti before next chunk's writes
  }

  // zero-fill truncated tail (masks exact; |w| <= 1e-4)
  for (int s2 = cproc * 256 + t; s2 < NS; s2 += 256) {
    out[OFF_W + rb + s2] = 0.0f;
    out[OFF_FULL + rb + s2] = 0.0f;
    out[OFF_INV + rb + s2] = 0.0f;
  }

  s_red[t] = dsum;
  __syncthreads();
  for (int off = 128; off > 0; off >>= 1) {
    if (t < off) s_red[t] += s_red[t + off];
    __syncthreads();
  }
  if (t == 0) {
    out[OFF_DEPTH + r] = s_red[0];
    out[OFF_BG + r] = s_bg;
  }
}

// spin grid-barrier: valid because all TOPK_NB=128 blocks are co-resident.
// __syncthreads drains this block's vmem (atomics performed at coherent point)
// before the ticket.
__device__ __forceinline__ void gbar(unsigned* ctr) {
  __syncthreads();
  if (threadIdx.x == 0) {
    TICKET(ctr);
    while (AGLD(ctr) < (unsigned)TOPK_NB) __builtin_amdgcn_s_sleep(8);
  }
  __syncthreads();
}

// suffix radix-find over nbins bins of global hist g (bin i at g[i*hs]).
// All blocks run this redundantly on identical data -> identical results.
// res[0]=sel bin, res[1]=count strictly above sel bin (base included).
// s_loc[0]=total+base.
__device__ void find_in(const unsigned* __restrict__ g, int nbins, int hs,
                        unsigned base, unsigned* sb, unsigned* s_loc,
                        unsigned* res, int t) {
  for (int i = t; i < nbins; i += 256) sb[i] = AGLD(&g[(size_t)i * hs]);
  __syncthreads();
  int C = nbins >> 8;
  unsigned csum = 0;
  int b0 = t * C;
  for (int k = 0; k < C; k++) csum += sb[b0 + k];
  s_loc[t] = csum;
  __syncthreads();
  for (int off = 1; off < 256; off <<= 1) {
    unsigned v = (t + off < 256) ? s_loc[t + off] : 0u;
    __syncthreads();
    s_loc[t] += v;
    __syncthreads();
  }
  if (t == 0) s_loc[0] += base;
  unsigned run = (t + 1 < 256) ? s_loc[t + 1] : 0u;
  for (int k = C - 1; k >= 0; k--) {
    unsigned nxt = run;
    run += sb[b0 + k];
    if (base + run >= TOPK && base + nxt < TOPK) {
      res[0] = (unsigned)(b0 + k);
      res[1] = base + nxt;
    }
  }
  __syncthreads();
}

// 128 blocks x 256 threads (round-11 tail, measured best). 3 gbars + a
// last-ticket tie patch (no 4th spin): P1 scan+LDS-capture+hist1 -> gbar ->
// find1 -> hist2 (from captures) -> gbar -> find2 -> hist3 -> gbar -> find3
// -> apply (from captures) -> ticket; last block patches ties, rest exit.
__global__ __launch_bounds__(256) void k_topk(
    float* __restrict__ out, unsigned* __restrict__ state,
    unsigned* __restrict__ h1, unsigned* __restrict__ h2,
    unsigned* __restrict__ h3, unsigned* __restrict__ tie, int hs) {
  __shared__ unsigned sh[2048];
  __shared__ unsigned s_loc[256];
  __shared__ unsigned res[2];
  __shared__ unsigned s_capu[CAPN];
  __shared__ unsigned s_capi[CAPN];
  __shared__ unsigned s_ccnt, s_ovf, s_last;
  int t = threadIdx.x;
  const uint4* sc4 = (const uint4*)(out + OFF_FULL);
  unsigned tb = 0u, M = 0u;

  // ---- P1: single full scan; LDS capture + LDS hist1 ----
  for (int i = t; i < 2048; i += 256) sh[i] = 0u;
  if (t == 0) { s_ccnt = 0u; s_ovf = 0u; }
  __syncthreads();
  for (int i = blockIdx.x * 256 + t; i < NEL4; i += TOPK_NB * 256) {
    uint4 v = sc4[i];
    #pragma unroll
    for (int c = 0; c < 4; ++c) {
      unsigned u = (c == 0) ? v.x : (c == 1) ? v.y : (c == 2) ? v.z : v.w;
      if (!u) continue;
      atomicAdd(&sh[u >> 21], 1u);
      unsigned p = atomicAdd(&s_ccnt, 1u);
      if (p < CAPN) { s_capu[p] = u; s_capi[p] = 4u * (unsigned)i + (unsigned)c; }
      else s_ovf = 1u;
    }
  }
  __syncthreads();
  for (int i = t; i < 2048; i += 256) {
    unsigned v = sh[i];
    if (v) atomicAdd(&h1[(size_t)i * hs], v);
  }
  if (t == 0 && s_ovf) AGST(&state[ST_OVF], 1u);
  unsigned ccnt = (s_ccnt < CAPN) ? s_ccnt : CAPN;
  gbar(&state[ST_TK1]);
  unsigned ovf = AGLD(&state[ST_OVF]);   // uniform across blocks
  find_in(h1, 2048, hs, 0u, sh, s_loc, res, t);
  bool done = (s_loc[0] < TOPK);         // all positives selected
  unsigned sel1 = 0u, base1 = 0u;
  if (!done) { sel1 = res[0]; base1 = res[1]; }
  __syncthreads();

  if (!done) {
    // ---- pass 2: bits 20..10 ----
    for (int i = t; i < 2048; i += 256) sh[i] = 0u;
    __syncthreads();
    if (ovf) {
      for (int i = blockIdx.x * 256 + t; i < NEL4; i += TOPK_NB * 256) {
        uint4 v = sc4[i];
        if (v.x && (v.x >> 21) == sel1) atomicAdd(&sh[(v.x >> 10) & 0x7FFu], 1u);
        if (v.y && (v.y >> 21) == sel1) atomicAdd(&sh[(v.y >> 10) & 0x7FFu], 1u);
        if (v.z && (v.z >> 21) == sel1) atomicAdd(&sh[(v.z >> 10) & 0x7FFu], 1u);
        if (v.w && (v.w >> 21) == sel1) atomicAdd(&sh[(v.w >> 10) & 0x7FFu], 1u);
      }
    } else {
      for (unsigned i = t; i < ccnt; i += 256) {
        unsigned u = s_capu[i];
        if ((u >> 21) == sel1) atomicAdd(&sh[(u >> 10) & 0x7FFu], 1u);
      }
    }
    __syncthreads();
    for (int i = t; i < 2048; i += 256) {
      unsigned v = sh[i];
      if (v) atomicAdd(&h2[(size_t)i * hs], v);
    }
    gbar(&state[ST_TK2]);
    find_in(h2, 2048, hs, base1, sh, s_loc, res, t);
    unsigned sel2 = res[0], base2 = res[1];
    __syncthreads();

    // ---- pass 3: bits 9..0 ----
    for (int i = t; i < 1024; i += 256) sh[i] = 0u;
    __syncthreads();
    unsigned sel12 = (sel1 << 11) | sel2;
    if (ovf) {
      for (int i = blockIdx.x * 256 + t; i < NEL4; i += TOPK_NB * 256) {
        uint4 v = sc4[i];
        if (v.x && (v.x >> 10) == sel12) atomicAdd(&sh[v.x & 0x3FFu], 1u);
        if (v.y && (v.y >> 10) == sel12) atomicAdd(&sh[v.y & 0x3FFu], 1u);
        if (v.z && (v.z >> 10) == sel12) atomicAdd(&sh[v.z & 0x3FFu], 1u);
        if (v.w && (v.w >> 10) == sel12) atomicAdd(&sh[v.w & 0x3FFu], 1u);
      }
    } else {
      for (unsigned i = t; i < ccnt; i += 256) {
        unsigned u = s_capu[i];
        if ((u >> 10) == sel12) atomicAdd(&sh[u & 0x3FFu], 1u);
      }
    }
    __syncthreads();
    for (int i = t; i < 1024; i += 256) {
      unsigned v = sh[i];
      if (v) atomicAdd(&h3[(size_t)i * hs], v);
    }
    gbar(&state[ST_TK3]);
    find_in(h3, 1024, hs, base2, sh, s_loc, res, t);
    tb = (sel1 << 21) | (sel2 << 10) | res[0];
    M = TOPK - res[1];
  }

  // ---- apply (zero slots already hold correct 0.0) ----
  if (ovf) {
    for (int i = blockIdx.x * 256 + t; i < NEL4; i += TOPK_NB * 256) {
      uint4 v = sc4[i];
      #pragma unroll
      for (int c = 0; c < 4; ++c) {
        unsigned u = (c == 0) ? v.x : (c == 1) ? v.y : (c == 2) ? v.z : v.w;
        if (!u) continue;
        unsigned idx = 4u * (unsigned)i + (unsigned)c;
        if (tb == 0u || u > tb) {
          out[OFF_FULL + idx] = 1.0f;
          out[OFF_INV + idx] = 0.0f;
        } else if (u == tb) {
          atomicExch(&out[OFF_FULL + idx], 0.0f);
          unsigned p = atomicAdd(&state[ST_TIEN], 1u);
          if (p < TIE_CAP) atomicExch(&tie[p], idx);
        } else {
          out[OFF_FULL + idx] = 0.0f;
        }
      }
    }
  } else {
    for (unsigned i = t; i < ccnt; i += 256) {
      unsigned u = s_capu[i];
      unsigned idx = s_capi[i];
      if (tb == 0u || u > tb) {
        out[OFF_FULL + idx] = 1.0f;
        out[OFF_INV + idx] = 0.0f;
      } else if (u == tb) {
        atomicExch(&out[OFF_FULL + idx], 0.0f);   // coherent: patch may overwrite
        unsigned p = atomicAdd(&state[ST_TIEN], 1u);
        if (p < TIE_CAP) atomicExch(&tie[p], idx);
      } else {
        out[OFF_FULL + idx] = 0.0f;
      }
    }
  }

  // ---- last-ticket tie patch (no 4th full-grid spin) ----
  // __syncthreads drains this block's tie atomics to the coherent point
  // before the ticket; the block drawing ticket NB-1 is provably last, so
  // every block's tie entries and TIEN are visible to it via AGLD.
  if (t == 0) s_last = (TICKET(&state[ST_TK4]) == (unsigned)(TOPK_NB - 1)) ? 1u : 0u;
  __syncthreads();
  if (!s_last) return;
  if (t == 0 && tb != 0u) {
    unsigned ntie = AGLD(&state[ST_TIEN]);
    if (ntie > TIE_CAP) ntie = TIE_CAP;
    unsigned m = M;
    if (m > ntie) m = ntie;
    for (unsigned k = 0; k < m; k++) {
      unsigned bi = k, bv = AGLD(&tie[k]);
      for (unsigned j = k + 1; j < ntie; j++) {
        unsigned v = AGLD(&tie[j]);
        if (v < bv) { bv = v; bi = j; }
      }
      unsigned tk = AGLD(&tie[k]);
      AGST(&tie[bi], tk);
      AGST(&tie[k], bv);
      atomicExch(&out[OFF_FULL + bv], 1.0f);
      atomicExch(&out[OFF_INV + bv], 0.0f);
    }
  }
}

extern "C" void kernel_launch(void* const* d_in, const int* in_sizes, int n_in,
                              void* d_out, int out_size, void* d_ws, size_t ws_size,
                              hipStream_t stream) {
  const float* ro = (const float*)d_in[0];
  const float* rd = (const float*)d_in[1];
  const float* dens = (const float*)d_in[2];
  const float* prb = (const float*)d_in[3];
  const float* alpv = (const float*)d_in[4];
  float* out = (float*)d_out;
  unsigned* ws = (unsigned*)d_ws;

  // hist bin stride (uints): 16 => 64B/bin spreads hot-bin merge atomics
  // across cache lines (round-8/9 contention lesson). Fallback if ws small.
  int hs = 16;
  size_t need_uints = 16 + (size_t)(2048 + 2048 + 1024) * 16 + TIE_CAP;
  if (ws_size < (need_uints + 1024) * 4) hs = 1;
  unsigned* h1 = ws + 16;
  unsigned* h2 = h1 + (size_t)2048 * hs;
  unsigned* h3 = h2 + (size_t)2048 * hs;
  unsigned* tie = h3 + (size_t)1024 * hs;
  size_t zero_uints = 16 + (size_t)(2048 + 2048 + 1024) * hs;

  hipMemsetAsync(ws, 0, zero_uints * sizeof(unsigned), stream);
  k_march<<<NRAYS, 256, 0, stream>>>(ro, rd, dens, prb, alpv, out);
  k_topk<<<TOPK_NB, 256, 0, stream>>>(out, ws, h1, h2, h3, tie, hs);
}

// Round 15
// 85.868 us; speedup vs baseline: 1.4755x; 1.0647x over previous
//
#include <hip/hip_runtime.h>
#include <math.h>

#pragma clang fp contract(off)

#define NRAYS 4096
#define NS 512
#define NEL (NRAYS * NS)          // 2097152
#define NEL4 (NEL / 4)            // 524288 uint4
#define TOPK 4000u
#define TOPK_NB 128
#define CAPN 5120                 // per-block LDS capture capacity

// d_out layout (floats), concatenated in reference return order
#define OFF_W     ((size_t)0)
#define OFF_BG    ((size_t)2097152)
#define OFF_DEPTH ((size_t)2101248)
#define OFF_FULL  ((size_t)2105344)
#define OFF_INV   ((size_t)4202496)

// ws state slots (uints)
#define ST_TIEN  6
#define ST_TK1   8
#define ST_TK2   9
#define ST_TK3   10
#define ST_TK4   11
#define ST_OVF   12
#define TIE_CAP  8192u

#define AGLD(p) __hip_atomic_load((p), __ATOMIC_RELAXED, __HIP_MEMORY_SCOPE_AGENT)
#define AGST(p, v) __hip_atomic_store((p), (v), __ATOMIC_RELAXED, __HIP_MEMORY_SCOPE_AGENT)
#define TICKET(p) __hip_atomic_fetch_add((p), 1u, __ATOMIC_RELAXED, __HIP_MEMORY_SCOPE_AGENT)

__device__ __forceinline__ float tri_sample(const float* __restrict__ vol, int R,
                                            float cx, float cy, float cz) {
  #pragma clang fp contract(off)
  float c0 = fminf(fmaxf(cx, -1.0f), 1.0f);
  float c1 = fminf(fmaxf(cy, -1.0f), 1.0f);
  float c2 = fminf(fmaxf(cz, -1.0f), 1.0f);
  float fR = (float)(R - 1);
  float x = (c0 + 1.0f) * 0.5f * fR;
  float y = (c1 + 1.0f) * 0.5f * fR;
  float z = (c2 + 1.0f) * 0.5f * fR;
  float xf = fminf(fmaxf(floorf(x), 0.0f), (float)(R - 2));
  float yf = fminf(fmaxf(floorf(y), 0.0f), (float)(R - 2));
  float zf = fminf(fmaxf(floorf(z), 0.0f), (float)(R - 2));
  int x0 = (int)xf, y0 = (int)yf, z0 = (int)zf;
  float xd = x - xf, yd = y - yf, zd = z - zf;
  const float* p = vol + ((size_t)z0 * R + (size_t)y0) * R + (size_t)x0;
  float c000 = p[0], c001 = p[1];
  float c010 = p[R], c011 = p[R + 1];
  const float* q = p + (size_t)R * R;
  float c100 = q[0], c101 = q[1];
  float c110 = q[R], c111 = q[R + 1];
  float omx = 1.0f - xd, omy = 1.0f - yd, omz = 1.0f - zd;
  float c00 = c000 * omx + c001 * xd;
  float c01 = c010 * omx + c011 * xd;
  float c10 = c100 * omx + c101 * xd;
  float c11 = c110 * omx + c111 * xd;
  float a0 = c00 * omy + c01 * yd;
  float a1 = c10 * omy + c11 * yd;
  return a0 * omz + a1 * zd;
}

// 4 exact left-to-right chain steps; stores inclusive products as one float4.
#define CH4(V, IDX)                                        \
  {                                                        \
    float t0_ = T * ((1.0f - (V).x) + 1e-10f);             \
    float t1_ = t0_ * ((1.0f - (V).y) + 1e-10f);           \
    float t2_ = t1_ * ((1.0f - (V).z) + 1e-10f);           \
    float t3_ = t2_ * ((1.0f - (V).w) + 1e-10f);           \
    Ti4[IDX] = make_float4(t0_, t1_, t2_, t3_);            \
    T = t3_;                                               \
  }

// Round-11 march (measured 56us, stable over 6 rounds): block per ray, 2
// chunks of 256 samples, all alpha+density gathers in parallel; prob gathered
// GATED in phase 2 (round-12: unconditional prob costs +75MB/+23us). t0-only
// pipelined cumprod, bit-exact numpy left-to-right rounding. Chunk-end early
// termination (T<=1e-4): processed chunks bit-exact; skipped samples have
// ref-w <= 1e-4 so mask bits exact, |depth err| <= ~7e-4 (threshold 4.4e-2).
// ZERO global atomics (round-8/9 lesson: hot-line atomics cost ~250us).
// NEW: first 128 blocks zero the ws region (replaces the hipMemsetAsync
// dispatch; kernel-boundary coherence orders these stores before k_topk).
__global__ __launch_bounds__(256) void k_march(
    const float* __restrict__ ro, const float* __restrict__ rd,
    const float* __restrict__ dens, const float* __restrict__ prb,
    const float* __restrict__ alpv, float* __restrict__ out,
    unsigned* __restrict__ ws, unsigned zu) {
  #pragma clang fp contract(off)
  const float STEP = (float)(3.0 * 1.7320508075688772 / 512.0);
  const float DIST = (float)((3.0 * 1.7320508075688772 / 512.0) * 25.0);
  const float INVG = 2.0f / 3.0f;
  int r = blockIdx.x;
  int t = threadIdx.x;
  __shared__ __align__(16) float s_alpha[272];   // 256 + 16 pad (prefetch overrun)
  __shared__ __align__(16) float s_Ti[256];      // inclusive products for chunk
  __shared__ float s_red[256];
  __shared__ float s_Tstart, s_bg;
  __shared__ unsigned s_term;

  // zero ws slice (blocks 0..127); ordered before k_topk by kernel boundary
  if (blockIdx.x < 128) {
    unsigned per = (zu + 127u) >> 7;
    unsigned b0 = (unsigned)blockIdx.x * per;
    unsigned e = b0 + per;
    if (e > zu) e = zu;
    for (unsigned i = b0 + (unsigned)t; i < e; i += 256u) ws[i] = 0u;
  }

  float ox = ro[r * 3 + 0], oy = ro[r * 3 + 1], oz = ro[r * 3 + 2];
  float dx = rd[r * 3 + 0], dy = rd[r * 3 + 1], dz = rd[r * 3 + 2];
  float vx = (dx == 0.0f) ? 1e-6f : dx;
  float vy = (dy == 0.0f) ? 1e-6f : dy;
  float vz = (dz == 0.0f) ? 1e-6f : dz;
  float tmin;
  {
    float rax = (1.5f - ox) / vx, rbx = (-1.5f - ox) / vx;
    float ray = (1.5f - oy) / vy, rby = (-1.5f - oy) / vy;
    float raz = (1.5f - oz) / vz, rbz = (-1.5f - oz) / vz;
    float m0 = fminf(rax, rbx), m1 = fminf(ray, rby), m2 = fminf(raz, rbz);
    tmin = fmaxf(fmaxf(m0, m1), m2);
    tmin = fminf(fmaxf(tmin, 2.0f), 6.0f);
  }

  unsigned rb = (unsigned)r * NS;
  float Tcarry = 1.0f;     // meaningful on t0 only
  float dsum = 0.0f;
  int cproc = 2;

  for (int c = 0; c < 2; ++c) {
    int s = c * 256 + t;
    float ts = tmin + STEP * (float)s;
    float px = ox + dx * ts;
    float py = oy + dy * ts;
    float pz = oz + dz * ts;
    bool inb = !((-1.5f > px) || (px > 1.5f) || (-1.5f > py) || (py > 1.5f) ||
                 (-1.5f > pz) || (pz > 1.5f));
    float a = 0.0f;
    float nx = 0.0f, ny = 0.0f, nz = 0.0f;
    if (inb) {
      nx = (px + 1.5f) * INVG - 1.0f;
      ny = (py + 1.5f) * INVG - 1.0f;
      nz = (pz + 1.5f) * INVG - 1.0f;
      float al = tri_sample(alpv, 128, nx, ny, nz);
      float feat = tri_sample(dens, 256, nx, ny, nz);  // independent chains overlap
      if (al > 0.001f) {
        float xx = feat + (-10.0f);
        float sp = fmaxf(xx, 0.0f) + log1pf(expf(-fabsf(xx)));
        a = 1.0f - expf(-(sp * DIST));
      }
    }
    s_alpha[t] = a;
    __syncthreads();

    // t0 pipelined serial cumprod: prefetch segment k+1 while chaining seg k.
    if (t == 0) {
      s_Tstart = Tcarry;
      float T = Tcarry;
      const float4* a4 = (const float4*)s_alpha;
      float4* Ti4 = (float4*)s_Ti;
      float4 A0 = a4[0], A1 = a4[1], A2 = a4[2], A3 = a4[3];
      for (int seg = 0; seg < 16; ++seg) {
        int nb = seg * 4 + 4;                  // pad makes seg=15 reads safe
        float4 B0 = a4[nb], B1 = a4[nb + 1], B2 = a4[nb + 2], B3 = a4[nb + 3];
        int i0 = seg * 4;
        CH4(A0, i0); CH4(A1, i0 + 1); CH4(A2, i0 + 2); CH4(A3, i0 + 3);
        A0 = B0; A1 = B1; A2 = B2; A3 = B3;
      }
      Tcarry = T;
      s_bg = T;
      s_term = (T <= 1e-4f) ? 1u : 0u;
    }
    __syncthreads();

    float Tpre = (t == 0) ? s_Tstart : s_Ti[t - 1];
    float w = a * Tpre;
    dsum += w * ts;
    float sc = 0.0f, app = 0.0f;
    if (w > 1e-4f) {
      app = 1.0f;
      float pv = tri_sample(prb, 256, nx, ny, nz);
      sc = w * pv;
    }
    out[OFF_W + rb + s] = w;
    out[OFF_FULL + rb + s] = sc;   // score stash (0.0 bits == final mask 0.0)
    out[OFF_INV + rb + s] = app;   // app stash (== final inv unless full)

    if (s_term) { cproc = c + 1; break; }   // uniform (read after barrier)
    __syncthreads();   // WAR: protect s_alpha/s_Ti before next chunk's writes
  }

  // zero-fill truncated tail (masks exact; |w| <= 1e-4), float4-vectorized
  {
    float4 z4 = make_float4(0.0f, 0.0f, 0.0f, 0.0f);
    for (int s2 = cproc * 256 + t * 4; s2 < NS; s2 += 1024) {
      *(float4*)&out[OFF_W + rb + s2] = z4;
      *(float4*)&out[OFF_FULL + rb + s2] = z4;
      *(float4*)&out[OFF_INV + rb + s2] = z4;
    }
  }

  s_red[t] = dsum;
  __syncthreads();
  for (int off = 128; off > 0; off >>= 1) {
    if (t < off) s_red[t] += s_red[t + off];
    __syncthreads();
  }
  if (t == 0) {
    out[OFF_DEPTH + r] = s_red[0];
    out[OFF_BG + r] = s_bg;
  }
}

// spin grid-barrier: valid because all TOPK_NB=128 blocks are co-resident.
// __syncthreads drains this block's vmem (atomics performed at coherent point)
// before the ticket.
__device__ __forceinline__ void gbar(unsigned* ctr) {
  __syncthreads();
  if (threadIdx.x == 0) {
    TICKET(ctr);
    while (AGLD(ctr) < (unsigned)TOPK_NB) __builtin_amdgcn_s_sleep(8);
  }
  __syncthreads();
}

// suffix radix-find over nbins bins of global hist g (bin i at g[i*hs]).
// All blocks run this redundantly on identical data -> identical results.
// res[0]=sel bin, res[1]=count strictly above sel bin (base included).
// s_loc[0]=total+base.
__device__ void find_in(const unsigned* __restrict__ g, int nbins, int hs,
                        unsigned base, unsigned* sb, unsigned* s_loc,
                        unsigned* res, int t) {
  for (int i = t; i < nbins; i += 256) sb[i] = AGLD(&g[(size_t)i * hs]);
  __syncthreads();
  int C = nbins >> 8;
  unsigned csum = 0;
  int b0 = t * C;
  for (int k = 0; k < C; k++) csum += sb[b0 + k];
  s_loc[t] = csum;
  __syncthreads();
  for (int off = 1; off < 256; off <<= 1) {
    unsigned v = (t + off < 256) ? s_loc[t + off] : 0u;
    __syncthreads();
    s_loc[t] += v;
    __syncthreads();
  }
  if (t == 0) s_loc[0] += base;
  unsigned run = (t + 1 < 256) ? s_loc[t + 1] : 0u;
  for (int k = C - 1; k >= 0; k--) {
    unsigned nxt = run;
    run += sb[b0 + k];
    if (base + run >= TOPK && base + nxt < TOPK) {
      res[0] = (unsigned)(b0 + k);
      res[1] = base + nxt;
    }
  }
  __syncthreads();
}

// 128 blocks x 256 threads (measured-best tail). 3 gbars + last-ticket tie
// patch: P1 scan+LDS-capture+hist1 -> gbar -> find1 -> hist2 (from captures)
// -> gbar -> find2 -> hist3 -> gbar -> find3 -> apply (from captures) ->
// ticket; last block patches ties, rest exit.
__global__ __launch_bounds__(256) void k_topk(
    float* __restrict__ out, unsigned* __restrict__ state,
    unsigned* __restrict__ h1, unsigned* __restrict__ h2,
    unsigned* __restrict__ h3, unsigned* __restrict__ tie, int hs) {
  __shared__ unsigned sh[2048];
  __shared__ unsigned s_loc[256];
  __shared__ unsigned res[2];
  __shared__ unsigned s_capu[CAPN];
  __shared__ unsigned s_capi[CAPN];
  __shared__ unsigned s_ccnt, s_ovf, s_last;
  int t = threadIdx.x;
  const uint4* sc4 = (const uint4*)(out + OFF_FULL);
  unsigned tb = 0u, M = 0u;

  // ---- P1: single full scan; LDS capture + LDS hist1 ----
  for (int i = t; i < 2048; i += 256) sh[i] = 0u;
  if (t == 0) { s_ccnt = 0u; s_ovf = 0u; }
  __syncthreads();
  for (int i = blockIdx.x * 256 + t; i < NEL4; i += TOPK_NB * 256) {
    uint4 v = sc4[i];
    #pragma unroll
    for (int c = 0; c < 4; ++c) {
      unsigned u = (c == 0) ? v.x : (c == 1) ? v.y : (c == 2) ? v.z : v.w;
      if (!u) continue;
      atomicAdd(&sh[u >> 21], 1u);
      unsigned p = atomicAdd(&s_ccnt, 1u);
      if (p < CAPN) { s_capu[p] = u; s_capi[p] = 4u * (unsigned)i + (unsigned)c; }
      else s_ovf = 1u;
    }
  }
  __syncthreads();
  for (int i = t; i < 2048; i += 256) {
    unsigned v = sh[i];
    if (v) atomicAdd(&h1[(size_t)i * hs], v);
  }
  if (t == 0 && s_ovf) AGST(&state[ST_OVF], 1u);
  unsigned ccnt = (s_ccnt < CAPN) ? s_ccnt : CAPN;
  gbar(&state[ST_TK1]);
  unsigned ovf = AGLD(&state[ST_OVF]);   // uniform across blocks
  find_in(h1, 2048, hs, 0u, sh, s_loc, res, t);
  bool done = (s_loc[0] < TOPK);         // all positives selected
  unsigned sel1 = 0u, base1 = 0u;
  if (!done) { sel1 = res[0]; base1 = res[1]; }
  __syncthreads();

  if (!done) {
    // ---- pass 2: bits 20..10 ----
    for (int i = t; i < 2048; i += 256) sh[i] = 0u;
    __syncthreads();
    if (ovf) {
      for (int i = blockIdx.x * 256 + t; i < NEL4; i += TOPK_NB * 256) {
        uint4 v = sc4[i];
        if (v.x && (v.x >> 21) == sel1) atomicAdd(&sh[(v.x >> 10) & 0x7FFu], 1u);
        if (v.y && (v.y >> 21) == sel1) atomicAdd(&sh[(v.y >> 10) & 0x7FFu], 1u);
        if (v.z && (v.z >> 21) == sel1) atomicAdd(&sh[(v.z >> 10) & 0x7FFu], 1u);
        if (v.w && (v.w >> 21) == sel1) atomicAdd(&sh[(v.w >> 10) & 0x7FFu], 1u);
      }
    } else {
      for (unsigned i = t; i < ccnt; i += 256) {
        unsigned u = s_capu[i];
        if ((u >> 21) == sel1) atomicAdd(&sh[(u >> 10) & 0x7FFu], 1u);
      }
    }
    __syncthreads();
    for (int i = t; i < 2048; i += 256) {
      unsigned v = sh[i];
      if (v) atomicAdd(&h2[(size_t)i * hs], v);
    }
    gbar(&state[ST_TK2]);
    find_in(h2, 2048, hs, base1, sh, s_loc, res, t);
    unsigned sel2 = res[0], base2 = res[1];
    __syncthreads();

    // ---- pass 3: bits 9..0 ----
    for (int i = t; i < 1024; i += 256) sh[i] = 0u;
    __syncthreads();
    unsigned sel12 = (sel1 << 11) | sel2;
    if (ovf) {
      for (int i = blockIdx.x * 256 + t; i < NEL4; i += TOPK_NB * 256) {
        uint4 v = sc4[i];
        if (v.x && (v.x >> 10) == sel12) atomicAdd(&sh[v.x & 0x3FFu], 1u);
        if (v.y && (v.y >> 10) == sel12) atomicAdd(&sh[v.y & 0x3FFu], 1u);
        if (v.z && (v.z >> 10) == sel12) atomicAdd(&sh[v.z & 0x3FFu], 1u);
        if (v.w && (v.w >> 10) == sel12) atomicAdd(&sh[v.w & 0x3FFu], 1u);
      }
    } else {
      for (unsigned i = t; i < ccnt; i += 256) {
        unsigned u = s_capu[i];
        if ((u >> 10) == sel12) atomicAdd(&sh[u & 0x3FFu], 1u);
      }
    }
    __syncthreads();
    for (int i = t; i < 1024; i += 256) {
      unsigned v = sh[i];
      if (v) atomicAdd(&h3[(size_t)i * hs], v);
    }
    gbar(&state[ST_TK3]);
    find_in(h3, 1024, hs, base2, sh, s_loc, res, t);
    tb = (sel1 << 21) | (sel2 << 10) | res[0];
    M = TOPK - res[1];
  }

  // ---- apply (zero slots already hold correct 0.0) ----
  if (ovf) {
    for (int i = blockIdx.x * 256 + t; i < NEL4; i += TOPK_NB * 256) {
      uint4 v = sc4[i];
      #pragma unroll
      for (int c = 0; c < 4; ++c) {
        unsigned u = (c == 0) ? v.x : (c == 1) ? v.y : (c == 2) ? v.z : v.w;
        if (!u) continue;
        unsigned idx = 4u * (unsigned)i + (unsigned)c;
        if (tb == 0u || u > tb) {
          out[OFF_FULL + idx] = 1.0f;
          out[OFF_INV + idx] = 0.0f;
        } else if (u == tb) {
          atomicExch(&out[OFF_FULL + idx], 0.0f);
          unsigned p = atomicAdd(&state[ST_TIEN], 1u);
          if (p < TIE_CAP) atomicExch(&tie[p], idx);
        } else {
          out[OFF_FULL + idx] = 0.0f;
        }
      }
    }
  } else {
    for (unsigned i = t; i < ccnt; i += 256) {
      unsigned u = s_capu[i];
      unsigned idx = s_capi[i];
      if (tb == 0u || u > tb) {
        out[OFF_FULL + idx] = 1.0f;
        out[OFF_INV + idx] = 0.0f;
      } else if (u == tb) {
        atomicExch(&out[OFF_FULL + idx], 0.0f);   // coherent: patch may overwrite
        unsigned p = atomicAdd(&state[ST_TIEN], 1u);
        if (p < TIE_CAP) atomicExch(&tie[p], idx);
      } else {
        out[OFF_FULL + idx] = 0.0f;
      }
    }
  }

  // ---- last-ticket tie patch (no 4th full-grid spin) ----
  // __syncthreads drains this block's tie atomics to the coherent point
  // before the ticket; the block drawing ticket NB-1 is provably last, so
  // every block's tie entries and TIEN are visible to it via AGLD.
  if (t == 0) s_last = (TICKET(&state[ST_TK4]) == (unsigned)(TOPK_NB - 1)) ? 1u : 0u;
  __syncthreads();
  if (!s_last) return;
  if (t == 0 && tb != 0u) {
    unsigned ntie = AGLD(&state[ST_TIEN]);
    if (ntie > TIE_CAP) ntie = TIE_CAP;
    unsigned m = M;
    if (m > ntie) m = ntie;
    for (unsigned k = 0; k < m; k++) {
      unsigned bi = k, bv = AGLD(&tie[k]);
      for (unsigned j = k + 1; j < ntie; j++) {
        unsigned v = AGLD(&tie[j]);
        if (v < bv) { bv = v; bi = j; }
      }
      unsigned tk = AGLD(&tie[k]);
      AGST(&tie[bi], tk);
      AGST(&tie[k], bv);
      atomicExch(&out[OFF_FULL + bv], 1.0f);
      atomicExch(&out[OFF_INV + bv], 0.0f);
    }
  }
}

extern "C" void kernel_launch(void* const* d_in, const int* in_sizes, int n_in,
                              void* d_out, int out_size, void* d_ws, size_t ws_size,
                              hipStream_t stream) {
  const float* ro = (const float*)d_in[0];
  const float* rd = (const float*)d_in[1];
  const float* dens = (const float*)d_in[2];
  const float* prb = (const float*)d_in[3];
  const float* alpv = (const float*)d_in[4];
  float* out = (float*)d_out;
  unsigned* ws = (unsigned*)d_ws;

  // hist bin stride (uints): 16 => 64B/bin spreads hot-bin merge atomics
  // across cache lines (round-8/9 contention lesson). Fallback if ws small.
  int hs = 16;
  size_t need_uints = 16 + (size_t)(2048 + 2048 + 1024) * 16 + TIE_CAP;
  if (ws_size < (need_uints + 1024) * 4) hs = 1;
  unsigned* h1 = ws + 16;
  unsigned* h2 = h1 + (size_t)2048 * hs;
  unsigned* h3 = h2 + (size_t)2048 * hs;
  unsigned* tie = h3 + (size_t)1024 * hs;
  unsigned zero_uints = (unsigned)(16 + (size_t)(2048 + 2048 + 1024) * hs);

  k_march<<<NRAYS, 256, 0, stream>>>(ro, rd, dens, prb, alpv, out, ws, zero_uints);
  k_topk<<<TOPK_NB, 256, 0, stream>>>(out, ws, h1, h2, h3, tie, hs);
}